// Round 1
// baseline (1471.739 us; speedup 1.0000x reference)
//
#include <hip/hip_runtime.h>

#define NPTS 2048
#define TPB  256
#define CPT  (NPTS / TPB)   // columns per thread = 8
#define NWAVES (TPB / 64)   // 4

// One block per batch. Sequential greedy matching; per row:
//  - each thread computes masked min over its 8 register-resident columns
//  - wave-level u64-key min reduce (6x shfl_xor)
//  - cross-wave min via double-buffered LDS (1 barrier per row)
__global__ __launch_bounds__(TPB) void emd_greedy_kernel(
    const float* __restrict__ pred, const float* __restrict__ target,
    float* __restrict__ batch_sums) {
  const int b   = blockIdx.x;
  const int tid = threadIdx.x;
  const float* p = pred   + (size_t)b * NPTS * 3;
  const float* t = target + (size_t)b * NPTS * 3;

  __shared__ float px[NPTS], py[NPTS], pz[NPTS], pq[NPTS];
  __shared__ unsigned long long wkey[2][NWAVES];

  // Stage pred points (and their squared norms) in LDS.
  for (int i = tid; i < NPTS; i += TPB) {
    float x = p[3 * i + 0], y = p[3 * i + 1], z = p[3 * i + 2];
    px[i] = x; py[i] = y; pz[i] = z;
    pq[i] = x * x + y * y + z * z;
  }

  // Own target columns j = tid + k*TPB in registers.
  float tx[CPT], ty[CPT], tz[CPT], tq[CPT];
#pragma unroll
  for (int k = 0; k < CPT; ++k) {
    int j = tid + k * TPB;
    float x = t[3 * j + 0], y = t[3 * j + 1], z = t[3 * j + 2];
    tx[k] = x; ty[k] = y; tz[k] = z;
    tq[k] = x * x + y * y + z * z;
  }
  unsigned int usedmask = 0;  // bit k set => column tid + k*TPB consumed
  float sum = 0.f;
  __syncthreads();

  for (int i = 0; i < NPTS; ++i) {
    const float X = px[i], Y = py[i], Z = pz[i], Q = pq[i];
    unsigned long long best = ~0ULL;
#pragma unroll
    for (int k = 0; k < CPT; ++k) {
      float dot = fmaf(tx[k], X, fmaf(ty[k], Y, tz[k] * Z));
      float d2  = Q + fmaf(-2.f, dot, tq[k]);
      d2 = fmaxf(d2, 1e-12f);  // clamp BEFORE compare: matches ref tie semantics
      // d2 >= 1e-12 > 0, so float bits order == numeric order.
      unsigned long long key =
          ((unsigned long long)__float_as_uint(d2) << 32) |
          (unsigned)(tid + k * TPB);
      if (usedmask & (1u << k)) key = ~0ULL;
      best = key < best ? key : best;
    }
    // Wave-level min reduce on the packed key (smallest index wins ties).
#pragma unroll
    for (int m = 1; m < 64; m <<= 1) {
      unsigned long long o = __shfl_xor(best, m, 64);
      best = o < best ? o : best;
    }
    const int wv = tid >> 6;
    const int ph = i & 1;  // double buffer: one barrier per row suffices
    if ((tid & 63) == 0) wkey[ph][wv] = best;
    __syncthreads();
    unsigned long long r = wkey[ph][0];
#pragma unroll
    for (int w = 1; w < NWAVES; ++w) {
      unsigned long long o = wkey[ph][w];
      r = o < r ? o : r;
    }
    const unsigned jstar = (unsigned)(r & 0xffffffffu);
    if (tid == (int)(jstar & (TPB - 1))) usedmask |= 1u << (jstar >> 8);
    if (tid == 0) sum += sqrtf(__uint_as_float((unsigned)(r >> 32)));
  }
  if (tid == 0) batch_sums[b] = sum;
}

// mean over batches of (per-batch sum / N)
__global__ void emd_finalize_kernel(const float* __restrict__ batch_sums,
                                    float* __restrict__ out, int B) {
  float acc = 0.f;
  for (int b = 0; b < B; ++b) acc += batch_sums[b] / (float)NPTS;
  out[0] = acc / (float)B;
}

extern "C" void kernel_launch(void* const* d_in, const int* in_sizes, int n_in,
                              void* d_out, int out_size, void* d_ws, size_t ws_size,
                              hipStream_t stream) {
  const float* pred   = (const float*)d_in[0];
  const float* target = (const float*)d_in[1];
  float* ws  = (float*)d_ws;
  float* out = (float*)d_out;
  const int B = in_sizes[0] / (NPTS * 3);

  emd_greedy_kernel<<<B, TPB, 0, stream>>>(pred, target, ws);
  emd_finalize_kernel<<<1, 1, 0, stream>>>(ws, out, B);
}

// Round 2
// 1314.491 us; speedup vs baseline: 1.1196x; 1.1196x over previous
//
#include <hip/hip_runtime.h>

#define NPTS 2048
#define CPL  32            // columns per lane (2048 / 64)
#define HCPL 16            // column pairs per lane

typedef float v2f __attribute__((ext_vector_type(2)));

static __device__ __forceinline__ unsigned umin2(unsigned a, unsigned b) {
  return a < b ? a : b;
}

// One wave (64 lanes) per batch; 8 independent blocks. No barriers in the
// row loop. Lane L owns columns j = L*32 .. L*32+31 in registers.
// Per row: packed-fp32 distance eval -> per-lane u32-key argmin ->
// DPP/swizzle wave min-reduce -> ballot picks winning lane (smallest j on
// ties) -> that lane clears its own column bit locally.
__global__ __launch_bounds__(64, 1) void emd_greedy_kernel(
    const float* __restrict__ pred, const float* __restrict__ target,
    float* __restrict__ batch_sums) {
  const int b    = blockIdx.x;
  const int lane = threadIdx.x;
  const float* p = pred   + (size_t)b * NPTS * 3;
  const float* t = target + (size_t)b * NPTS * 3;

  __shared__ float px[NPTS + 1], py[NPTS + 1], pz[NPTS + 1], pq[NPTS + 1];
  for (int i = lane; i < NPTS; i += 64) {
    float x = p[3 * i + 0], y = p[3 * i + 1], z = p[3 * i + 2];
    px[i] = x; py[i] = y; pz[i] = z;
    pq[i] = x * x + y * y + z * z;
  }
  // px[NPTS]... left uninitialized: prefetched on the last iteration but
  // never consumed.

  // Own target columns (contiguous per lane) in registers, as float2 pairs.
  v2f TX[HCPL], TY[HCPL], TZ[HCPL], TQ[HCPL];
  const float* tb = t + (size_t)lane * CPL * 3;
#pragma unroll
  for (int h = 0; h < HCPL; ++h) {
    float x0 = tb[6 * h + 0], y0 = tb[6 * h + 1], z0 = tb[6 * h + 2];
    float x1 = tb[6 * h + 3], y1 = tb[6 * h + 4], z1 = tb[6 * h + 5];
    TX[h] = (v2f){x0, x1};
    TY[h] = (v2f){y0, y1};
    TZ[h] = (v2f){z0, z1};
    TQ[h] = (v2f){x0 * x0 + y0 * y0 + z0 * z0,
                  x1 * x1 + y1 * y1 + z1 * z1};
  }
  unsigned usedmask = 0;  // bit k set => column lane*32+k consumed
  float sum = 0.f;
  __syncthreads();  // once: pred staging visible to whole wave (4 waves? no - 1 wave, but keep for LDS ordering)

  float X = px[0], Y = py[0], Z = pz[0], Q = pq[0];
  for (int i = 0; i < NPTS; ++i) {
    // Prefetch next pred point (consumed next iteration).
    float Xn = px[i + 1], Yn = py[i + 1], Zn = pz[i + 1], Qn = pq[i + 1];

    const v2f Xv = {X, X}, Yv = {Y, Y}, Zv = {Z, Z};
    unsigned bestu = 0xFFFFFFFFu;
    int bestk = 0;
#pragma unroll
    for (int h = 0; h < HCPL; ++h) {
      // Same fp32 op order as the round-0 kernel (absmax was exactly 0):
      // dot = fmaf(tx, X, fmaf(ty, Y, tz*Z)); d2 = Q + fmaf(-2, dot, tq)
#if __has_builtin(__builtin_elementwise_fma)
      v2f dot = __builtin_elementwise_fma(
          TX[h], Xv, __builtin_elementwise_fma(TY[h], Yv, TZ[h] * Zv));
      v2f dd = __builtin_elementwise_fma((v2f){-2.f, -2.f}, dot, TQ[h]);
      float d0 = Q + dd.x;
      float d1 = Q + dd.y;
#else
      float dot0 = fmaf(TX[h].x, X, fmaf(TY[h].x, Y, TZ[h].x * Z));
      float dot1 = fmaf(TX[h].y, X, fmaf(TY[h].y, Y, TZ[h].y * Z));
      float d0 = Q + fmaf(-2.f, dot0, TQ[h].x);
      float d1 = Q + fmaf(-2.f, dot1, TQ[h].y);
#endif
      // u32 key: positive-float bits order == numeric order.
      // Used column -> key = 0xFFFFFFFF via 1-bit sign-extend OR.
      unsigned s0 = (unsigned)(((int)(usedmask << (31 - (2 * h + 0)))) >> 31);
      unsigned s1 = (unsigned)(((int)(usedmask << (31 - (2 * h + 1)))) >> 31);
      unsigned u0 = (unsigned)__float_as_int(d0) | s0;
      unsigned u1 = (unsigned)__float_as_int(d1) | s1;
      // Pair tournament; strict < keeps the earlier index on exact ties.
      unsigned pu = u0;
      int pk = 2 * h;
      if (u1 < u0) { pu = u1; pk = 2 * h + 1; }
      if (pu < bestu) { bestu = pu; bestk = pk; }
    }

    // Wave-wide min of the u32 keys: 4 DPP steps + ds_swizzle + shfl_xor.
    unsigned m = bestu;
    m = umin2(m, (unsigned)__builtin_amdgcn_mov_dpp((int)m, 0xB1, 0xF, 0xF, true));   // xor 1 (quad_perm 1,0,3,2)
    m = umin2(m, (unsigned)__builtin_amdgcn_mov_dpp((int)m, 0x4E, 0xF, 0xF, true));   // xor 2 (quad_perm 2,3,0,1)
    m = umin2(m, (unsigned)__builtin_amdgcn_mov_dpp((int)m, 0x141, 0xF, 0xF, true));  // xor 4 (row_half_mirror)
    m = umin2(m, (unsigned)__builtin_amdgcn_mov_dpp((int)m, 0x140, 0xF, 0xF, true));  // xor 8 (row_mirror)
    m = umin2(m, (unsigned)__builtin_amdgcn_ds_swizzle((int)m, 0x401F));              // xor 16
    m = umin2(m, (unsigned)__shfl_xor((int)m, 32, 64));                               // xor 32

    // Winning lane = smallest lane with key == m (= smallest column j on
    // exact ties, since columns are lane-major). It flips its own bit.
    unsigned long long mk = __ballot(bestu == m);
    int first = __ffsll(mk) - 1;
    if (lane == first) usedmask |= 1u << bestk;

    sum += sqrtf(fmaxf(__uint_as_float(m), 1e-12f));
    X = Xn; Y = Yn; Z = Zn; Q = Qn;
  }
  if (lane == 0) batch_sums[b] = sum;
}

// mean over batches of (per-batch sum / N)
__global__ void emd_finalize_kernel(const float* __restrict__ batch_sums,
                                    float* __restrict__ out, int B) {
  float acc = 0.f;
  for (int b = 0; b < B; ++b) acc += batch_sums[b] / (float)NPTS;
  out[0] = acc / (float)B;
}

extern "C" void kernel_launch(void* const* d_in, const int* in_sizes, int n_in,
                              void* d_out, int out_size, void* d_ws, size_t ws_size,
                              hipStream_t stream) {
  const float* pred   = (const float*)d_in[0];
  const float* target = (const float*)d_in[1];
  float* ws  = (float*)d_ws;
  float* out = (float*)d_out;
  const int B = in_sizes[0] / (NPTS * 3);

  emd_greedy_kernel<<<B, 64, 0, stream>>>(pred, target, ws);
  emd_finalize_kernel<<<1, 1, 0, stream>>>(ws, out, B);
}